// Round 1
// baseline (164.439 us; speedup 1.0000x reference)
//
#include <hip/hip_runtime.h>
#include <math.h>

#define BB 128
#define HH 64
#define WW 64
#define LH 150
#define KK 30
#define PW 66          // padded LDS row stride (64 + 2 border)
#define NTHREADS 512

// Block = one image. Threads: 32 col-groups (2 cols each) x 16 row-groups (4 rows each).
// Each thread owns an 8-pixel tile (4 rows x 2 cols).
__global__ __launch_bounds__(NTHREADS, 2)
void vin_kernel(const float* __restrict__ layout,
                const float* __restrict__ heatmap,
                const float* __restrict__ h_w,
                const float* __restrict__ h_b,
                const float* __restrict__ r_w,
                const float* __restrict__ q_w,
                const float* __restrict__ w,
                const float* __restrict__ fc_w,
                const int* __restrict__ S1,
                const int* __restrict__ S2,
                float* __restrict__ out)
{
    const int b   = blockIdx.x;
    const int tid = threadIdx.x;
    const int tx  = tid & 31;   // 0..31
    const int ty  = tid >> 5;   // 0..15
    const int x0  = tx * 2;
    const int y0  = ty * 4;

    __shared__ float rh_s[28];        // collapsed conv weights (3x3x3) + bias
    __shared__ float r_s[PW * PW];
    __shared__ float va[PW * PW];
    __shared__ float vb[PW * PW];

    // ---- collapse h-conv + 1x1 r-conv into a single 3->1 channel 3x3 conv ----
    // rh[i*9+t] = sum_c r_w[c] * h_w[c,i,t];  rh[27] = sum_c r_w[c] * h_b[c]
    if (tid < 28) {
        float s = 0.f;
        if (tid < 27) {
            for (int c = 0; c < LH; ++c) s += r_w[c] * h_w[c * 27 + tid];
        } else {
            for (int c = 0; c < LH; ++c) s += r_w[c] * h_b[c];
        }
        rh_s[tid] = s;
    }
    // zero LDS (so borders stay 0 forever; interiors get overwritten)
    for (int i = tid; i < PW * PW; i += NTHREADS) {
        r_s[i] = 0.f; va[i] = 0.f; vb[i] = 0.f;
    }
    __syncthreads();

    // ---- r = conv3x3(X, rh) + rb at my 8 pixels ----
    {
        const float* X0 = layout  + (size_t)b * 2 * HH * WW;
        const float* X1 = X0 + HH * WW;
        const float* X2 = heatmap + (size_t)b * HH * WW;
        const float rb_ = rh_s[27];
        #pragma unroll
        for (int p = 0; p < 8; ++p) {
            const int y = y0 + (p >> 1);
            const int x = x0 + (p & 1);
            float acc = rb_;
            #pragma unroll
            for (int dy = 0; dy < 3; ++dy) {
                const int yy = y + dy - 1;
                const bool yok = (yy >= 0) && (yy < HH);
                #pragma unroll
                for (int dx = 0; dx < 3; ++dx) {
                    const int xx = x + dx - 1;
                    const bool ok = yok && (xx >= 0) && (xx < WW);
                    const int gi = yy * WW + xx;
                    float x0v = ok ? X0[gi] : 0.f;
                    float x1v = ok ? X1[gi] : 0.f;
                    float x2v = ok ? X2[gi] : 0.f;
                    acc = fmaf(rh_s[0 * 9 + dy * 3 + dx], x0v, acc);
                    acc = fmaf(rh_s[1 * 9 + dy * 3 + dx], x1v, acc);
                    acc = fmaf(rh_s[2 * 9 + dy * 3 + dx], x2v, acc);
                }
            }
            r_s[(y + 1) * PW + (x + 1)] = acc;
        }
    }
    __syncthreads();

    // ---- rq[p][o] = conv3x3(r, q_w) at my pixels (constant across VI iters);
    //      v0 = max_o rq  (this IS the first q/v step of the reference) ----
    float rq[8][16];
    {
        float rn[6][4];
        #pragma unroll
        for (int i = 0; i < 6; ++i) {
            #pragma unroll
            for (int j = 0; j < 4; ++j)
                rn[i][j] = r_s[(y0 + i) * PW + (x0 + j)];
        }
        float vmax0[8];
        #pragma unroll
        for (int o = 0; o < 16; ++o) {
            float q9[9];
            #pragma unroll
            for (int t = 0; t < 9; ++t) q9[t] = q_w[o * 9 + t];
            #pragma unroll
            for (int p = 0; p < 8; ++p) {
                const int py = p >> 1, pxi = p & 1;
                float acc = 0.f;
                #pragma unroll
                for (int dy = 0; dy < 3; ++dy) {
                    #pragma unroll
                    for (int dx = 0; dx < 3; ++dx)
                        acc = fmaf(q9[dy * 3 + dx], rn[py + dy][pxi + dx], acc);
                }
                rq[p][o] = acc;
                vmax0[p] = (o == 0) ? acc : fmaxf(vmax0[p], acc);
            }
        }
        #pragma unroll
        for (int p = 0; p < 8; ++p)
            va[(y0 + (p >> 1) + 1) * PW + (x0 + (p & 1) + 1)] = vmax0[p];
    }
    __syncthreads();

    // ---- 29 value-iteration sweeps: q[o] = rq[o] + conv3x3(v, w[o]); v = max_o q ----
    float* vcur = va;
    float* vnxt = vb;
    #pragma unroll 1
    for (int it = 0; it < KK - 1; ++it) {
        float vn[6][4];
        #pragma unroll
        for (int i = 0; i < 6; ++i) {
            #pragma unroll
            for (int j = 0; j < 4; ++j)
                vn[i][j] = vcur[(y0 + i) * PW + (x0 + j)];
        }
        float vmax2[8];
        #pragma unroll
        for (int o = 0; o < 16; ++o) {
            float w9[9];
            #pragma unroll
            for (int t = 0; t < 9; ++t) w9[t] = w[o * 9 + t];
            #pragma unroll
            for (int p = 0; p < 8; ++p) {
                const int py = p >> 1, pxi = p & 1;
                float acc = rq[p][o];
                #pragma unroll
                for (int dy = 0; dy < 3; ++dy) {
                    #pragma unroll
                    for (int dx = 0; dx < 3; ++dx)
                        acc = fmaf(w9[dy * 3 + dx], vn[py + dy][pxi + dx], acc);
                }
                vmax2[p] = (o == 0) ? acc : fmaxf(vmax2[p], acc);
            }
        }
        #pragma unroll
        for (int p = 0; p < 8; ++p)
            vnxt[(y0 + (p >> 1) + 1) * PW + (x0 + (p & 1) + 1)] = vmax2[p];
        __syncthreads();
        float* t = vcur; vcur = vnxt; vnxt = t;
    }

    // ---- outputs: v, r, heatmap (coalesced), logits/probs (one thread) ----
    {
        float*       out_v = out + 1024 + (size_t)b * HH * WW;
        float*       out_r = out + 1024 + (size_t)BB * HH * WW + (size_t)b * HH * WW;
        float*       out_h = out + 1024 + (size_t)2 * BB * HH * WW + (size_t)b * HH * WW;
        const float* heat  = heatmap + (size_t)b * HH * WW;
        for (int i = tid; i < HH * WW; i += NTHREADS) {
            const int y = i >> 6, x = i & 63;
            out_v[i] = vcur[(y + 1) * PW + (x + 1)];
            out_r[i] = r_s[(y + 1) * PW + (x + 1)];
            out_h[i] = heat[i];
        }

        const int s1 = S1[b];
        const int s2 = S2[b];
        if (ty == (s1 >> 2) && tx == (s2 >> 1)) {
            // final conv evaluated at the single readout pixel
            float q16[16];
            #pragma unroll
            for (int o = 0; o < 16; ++o) {
                float acc = 0.f;
                #pragma unroll
                for (int dy = 0; dy < 3; ++dy) {
                    #pragma unroll
                    for (int dx = 0; dx < 3; ++dx) {
                        acc = fmaf(q_w[o * 9 + dy * 3 + dx], r_s[(s1 + dy) * PW + (s2 + dx)], acc);
                        acc = fmaf(w[o * 9 + dy * 3 + dx],  vcur[(s1 + dy) * PW + (s2 + dx)], acc);
                    }
                }
                q16[o] = acc;
            }
            float lg[4];
            #pragma unroll
            for (int j = 0; j < 4; ++j) {
                float a = 0.f;
                #pragma unroll
                for (int o = 0; o < 16; ++o) a = fmaf(fc_w[j * 16 + o], q16[o], a);
                lg[j] = a;
            }
            const float m  = fmaxf(fmaxf(lg[0], lg[1]), fmaxf(lg[2], lg[3]));
            const float e0 = expf(lg[0] - m), e1 = expf(lg[1] - m);
            const float e2 = expf(lg[2] - m), e3 = expf(lg[3] - m);
            const float s  = e0 + e1 + e2 + e3;
            out[b * 4 + 0] = lg[0]; out[b * 4 + 1] = lg[1];
            out[b * 4 + 2] = lg[2]; out[b * 4 + 3] = lg[3];
            out[512 + b * 4 + 0] = e0 / s; out[512 + b * 4 + 1] = e1 / s;
            out[512 + b * 4 + 2] = e2 / s; out[512 + b * 4 + 3] = e3 / s;
        }
    }
}

extern "C" void kernel_launch(void* const* d_in, const int* in_sizes, int n_in,
                              void* d_out, int out_size, void* d_ws, size_t ws_size,
                              hipStream_t stream) {
    const float* layout  = (const float*)d_in[0];
    const float* heatmap = (const float*)d_in[1];
    const float* h_w     = (const float*)d_in[2];
    const float* h_b     = (const float*)d_in[3];
    const float* r_w     = (const float*)d_in[4];
    const float* q_w     = (const float*)d_in[5];
    const float* w       = (const float*)d_in[6];
    const float* fc_w    = (const float*)d_in[7];
    const int*   S1      = (const int*)d_in[8];
    const int*   S2      = (const int*)d_in[9];
    float* out = (float*)d_out;

    hipLaunchKernelGGL(vin_kernel, dim3(BB), dim3(NTHREADS), 0, stream,
                       layout, heatmap, h_w, h_b, r_w, q_w, w, fc_w, S1, S2, out);
}

// Round 2
// 163.657 us; speedup vs baseline: 1.0048x; 1.0048x over previous
//
#include <hip/hip_runtime.h>
#include <math.h>

#define BB 128
#define HH 64
#define WW 64
#define LH 150
#define KK 30
#define PW 66          // padded LDS row stride (64 + 2 border)
#define NT 1024

// Block = one image. 1024 threads: tx = tid&63 (column), ty = tid>>6 (row group),
// each thread owns 4 pixels (rows y0..y0+3, column tx).
// rq[16][4] (64 VGPRs) is kept strictly statically indexed via macro expansion.

// One VI channel step: acc = BASE + conv3x3(vn, w[o]); vmax update.
#define CH_STEP(o, WSRC, BASEo, VMAX)                                   \
  do {                                                                  \
    const float* wp_ = (WSRC) + (o) * 9;                                \
    const float w0_ = wp_[0], w1_ = wp_[1], w2_ = wp_[2];               \
    const float w3_ = wp_[3], w4_ = wp_[4], w5_ = wp_[5];               \
    const float w6_ = wp_[6], w7_ = wp_[7], w8_ = wp_[8];               \
    _Pragma("unroll")                                                   \
    for (int p_ = 0; p_ < 4; ++p_) {                                    \
      float a_ = BASEo;                                                 \
      a_ = fmaf(w0_, vn[p_ + 0][0], a_);                                \
      a_ = fmaf(w1_, vn[p_ + 0][1], a_);                                \
      a_ = fmaf(w2_, vn[p_ + 0][2], a_);                                \
      a_ = fmaf(w3_, vn[p_ + 1][0], a_);                                \
      a_ = fmaf(w4_, vn[p_ + 1][1], a_);                                \
      a_ = fmaf(w5_, vn[p_ + 1][2], a_);                                \
      a_ = fmaf(w6_, vn[p_ + 2][0], a_);                                \
      a_ = fmaf(w7_, vn[p_ + 2][1], a_);                                \
      a_ = fmaf(w8_, vn[p_ + 2][2], a_);                                \
      POST_##o(p_, a_, VMAX);                                           \
    }                                                                   \
  } while (0)

__global__ __launch_bounds__(NT, 4)
void vin_kernel(const float* __restrict__ layout,
                const float* __restrict__ heatmap,
                const float* __restrict__ h_w,
                const float* __restrict__ h_b,
                const float* __restrict__ r_w,
                const float* __restrict__ q_w,
                const float* __restrict__ w,
                const float* __restrict__ fc_w,
                const int* __restrict__ S1,
                const int* __restrict__ S2,
                float* __restrict__ out)
{
    const int b   = blockIdx.x;
    const int tid = threadIdx.x;
    const int tx  = tid & 63;
    const int ty  = tid >> 6;
    const int y0  = ty * 4;

    __shared__ float rh_s[28];
    __shared__ float sA[PW * PW];   // X0, then r
    __shared__ float sB[PW * PW];   // X1, then v ping
    __shared__ float sC[PW * PW];   // X2, then v pong

    // collapse 150-ch h-conv + 1x1 r-conv into one 3->1 channel 3x3 conv
    if (tid < 28) {
        float s = 0.f;
        if (tid < 27) {
            for (int c = 0; c < LH; ++c) s += r_w[c] * h_w[c * 27 + tid];
        } else {
            for (int c = 0; c < LH; ++c) s += r_w[c] * h_b[c];
        }
        rh_s[tid] = s;
    }
    for (int i = tid; i < PW * PW; i += NT) { sA[i] = 0.f; sB[i] = 0.f; sC[i] = 0.f; }
    __syncthreads();

    // ---- stage X (3 channels) into LDS with zero halo ----
    {
        const float* X0 = layout  + (size_t)b * 2 * HH * WW;
        const float* X1 = X0 + HH * WW;
        const float* X2 = heatmap + (size_t)b * HH * WW;
        for (int i = tid; i < HH * WW; i += NT) {
            const int y = i >> 6, x = i & 63;
            const int d = (y + 1) * PW + (x + 1);
            sA[d] = X0[i]; sB[d] = X1[i]; sC[d] = X2[i];
        }
    }
    __syncthreads();

    // ---- r = conv3x3(X, rh) + rb at my 4 pixels ----
    float r4[4];
    {
        const float rb_ = rh_s[27];
        #pragma unroll
        for (int p = 0; p < 4; ++p) r4[p] = rb_;
        #pragma unroll
        for (int c = 0; c < 3; ++c) {
            const float* S = (c == 0) ? sA : ((c == 1) ? sB : sC);
            float xn[6][3];
            #pragma unroll
            for (int i = 0; i < 6; ++i)
                #pragma unroll
                for (int j = 0; j < 3; ++j)
                    xn[i][j] = S[(y0 + i) * PW + (tx + j)];
            #pragma unroll
            for (int p = 0; p < 4; ++p) {
                #pragma unroll
                for (int dy = 0; dy < 3; ++dy)
                    #pragma unroll
                    for (int dx = 0; dx < 3; ++dx)
                        r4[p] = fmaf(rh_s[c * 9 + dy * 3 + dx], xn[p + dy][dx], r4[p]);
            }
        }
    }
    __syncthreads();
    #pragma unroll
    for (int p = 0; p < 4; ++p) sA[(y0 + p + 1) * PW + (tx + 1)] = r4[p];
    __syncthreads();

    // ---- rq[o][p] = conv3x3(r, q_w); v0 = max_o rq ----
    float rq[16][4];
    float vmax[4];

#define POST_RQ(o, p, a, VM) do { rq[o][p] = (a); if ((o) == 0) VM[p] = (a); else VM[p] = fmaxf(VM[p], (a)); } while (0)
#define POST_0(p,a,VM)  POST_RQ(0,p,a,VM)
#define POST_1(p,a,VM)  POST_RQ(1,p,a,VM)
#define POST_2(p,a,VM)  POST_RQ(2,p,a,VM)
#define POST_3(p,a,VM)  POST_RQ(3,p,a,VM)
#define POST_4(p,a,VM)  POST_RQ(4,p,a,VM)
#define POST_5(p,a,VM)  POST_RQ(5,p,a,VM)
#define POST_6(p,a,VM)  POST_RQ(6,p,a,VM)
#define POST_7(p,a,VM)  POST_RQ(7,p,a,VM)
#define POST_8(p,a,VM)  POST_RQ(8,p,a,VM)
#define POST_9(p,a,VM)  POST_RQ(9,p,a,VM)
#define POST_10(p,a,VM) POST_RQ(10,p,a,VM)
#define POST_11(p,a,VM) POST_RQ(11,p,a,VM)
#define POST_12(p,a,VM) POST_RQ(12,p,a,VM)
#define POST_13(p,a,VM) POST_RQ(13,p,a,VM)
#define POST_14(p,a,VM) POST_RQ(14,p,a,VM)
#define POST_15(p,a,VM) POST_RQ(15,p,a,VM)

    {
        float vn[6][3];
        #pragma unroll
        for (int i = 0; i < 6; ++i)
            #pragma unroll
            for (int j = 0; j < 3; ++j)
                vn[i][j] = sA[(y0 + i) * PW + (tx + j)];
        CH_STEP(0,  q_w, 0.f, vmax);  CH_STEP(1,  q_w, 0.f, vmax);
        CH_STEP(2,  q_w, 0.f, vmax);  CH_STEP(3,  q_w, 0.f, vmax);
        CH_STEP(4,  q_w, 0.f, vmax);  CH_STEP(5,  q_w, 0.f, vmax);
        CH_STEP(6,  q_w, 0.f, vmax);  CH_STEP(7,  q_w, 0.f, vmax);
        CH_STEP(8,  q_w, 0.f, vmax);  CH_STEP(9,  q_w, 0.f, vmax);
        CH_STEP(10, q_w, 0.f, vmax);  CH_STEP(11, q_w, 0.f, vmax);
        CH_STEP(12, q_w, 0.f, vmax);  CH_STEP(13, q_w, 0.f, vmax);
        CH_STEP(14, q_w, 0.f, vmax);  CH_STEP(15, q_w, 0.f, vmax);
        #pragma unroll
        for (int p = 0; p < 4; ++p) sB[(y0 + p + 1) * PW + (tx + 1)] = vmax[p];
    }
    __syncthreads();

#undef POST_0
#undef POST_1
#undef POST_2
#undef POST_3
#undef POST_4
#undef POST_5
#undef POST_6
#undef POST_7
#undef POST_8
#undef POST_9
#undef POST_10
#undef POST_11
#undef POST_12
#undef POST_13
#undef POST_14
#undef POST_15

#define POST_VI(o, p, a, VM) do { if ((o) == 0) VM[p] = (a); else VM[p] = fmaxf(VM[p], (a)); } while (0)
#define POST_0(p,a,VM)  POST_VI(0,p,a,VM)
#define POST_1(p,a,VM)  POST_VI(1,p,a,VM)
#define POST_2(p,a,VM)  POST_VI(2,p,a,VM)
#define POST_3(p,a,VM)  POST_VI(3,p,a,VM)
#define POST_4(p,a,VM)  POST_VI(4,p,a,VM)
#define POST_5(p,a,VM)  POST_VI(5,p,a,VM)
#define POST_6(p,a,VM)  POST_VI(6,p,a,VM)
#define POST_7(p,a,VM)  POST_VI(7,p,a,VM)
#define POST_8(p,a,VM)  POST_VI(8,p,a,VM)
#define POST_9(p,a,VM)  POST_VI(9,p,a,VM)
#define POST_10(p,a,VM) POST_VI(10,p,a,VM)
#define POST_11(p,a,VM) POST_VI(11,p,a,VM)
#define POST_12(p,a,VM) POST_VI(12,p,a,VM)
#define POST_13(p,a,VM) POST_VI(13,p,a,VM)
#define POST_14(p,a,VM) POST_VI(14,p,a,VM)
#define POST_15(p,a,VM) POST_VI(15,p,a,VM)

    // ---- 29 value-iteration sweeps ----
    float* vcur = sB;
    float* vnxt = sC;
    #pragma unroll 1
    for (int it = 0; it < KK - 1; ++it) {
        float vn[6][3];
        #pragma unroll
        for (int i = 0; i < 6; ++i)
            #pragma unroll
            for (int j = 0; j < 3; ++j)
                vn[i][j] = vcur[(y0 + i) * PW + (tx + j)];
        float vm2[4];
        CH_STEP(0,  w, rq[0][p_],  vm2);  CH_STEP(1,  w, rq[1][p_],  vm2);
        CH_STEP(2,  w, rq[2][p_],  vm2);  CH_STEP(3,  w, rq[3][p_],  vm2);
        CH_STEP(4,  w, rq[4][p_],  vm2);  CH_STEP(5,  w, rq[5][p_],  vm2);
        CH_STEP(6,  w, rq[6][p_],  vm2);  CH_STEP(7,  w, rq[7][p_],  vm2);
        CH_STEP(8,  w, rq[8][p_],  vm2);  CH_STEP(9,  w, rq[9][p_],  vm2);
        CH_STEP(10, w, rq[10][p_], vm2);  CH_STEP(11, w, rq[11][p_], vm2);
        CH_STEP(12, w, rq[12][p_], vm2);  CH_STEP(13, w, rq[13][p_], vm2);
        CH_STEP(14, w, rq[14][p_], vm2);  CH_STEP(15, w, rq[15][p_], vm2);
        #pragma unroll
        for (int p = 0; p < 4; ++p) vnxt[(y0 + p + 1) * PW + (tx + 1)] = vm2[p];
        __syncthreads();
        float* t = vcur; vcur = vnxt; vnxt = t;
    }

    // ---- outputs ----
    {
        float*       out_v = out + 1024 + (size_t)b * HH * WW;
        float*       out_r = out + 1024 + (size_t)BB * HH * WW + (size_t)b * HH * WW;
        float*       out_h = out + 1024 + (size_t)2 * BB * HH * WW + (size_t)b * HH * WW;
        const float* heat  = heatmap + (size_t)b * HH * WW;
        for (int i = tid; i < HH * WW; i += NT) {
            const int y = i >> 6, x = i & 63;
            out_v[i] = vcur[(y + 1) * PW + (x + 1)];
            out_r[i] = sA[(y + 1) * PW + (x + 1)];
            out_h[i] = heat[i];
        }

        if (tid == 0) {
            const int s1 = S1[b];
            const int s2 = S2[b];
            float q16[16];
            #pragma unroll
            for (int o = 0; o < 16; ++o) {
                float acc = 0.f;
                #pragma unroll
                for (int dy = 0; dy < 3; ++dy)
                    #pragma unroll
                    for (int dx = 0; dx < 3; ++dx) {
                        acc = fmaf(q_w[o * 9 + dy * 3 + dx], sA[(s1 + dy) * PW + (s2 + dx)], acc);
                        acc = fmaf(w[o * 9 + dy * 3 + dx],  vcur[(s1 + dy) * PW + (s2 + dx)], acc);
                    }
                q16[o] = acc;
            }
            float lg[4];
            #pragma unroll
            for (int j = 0; j < 4; ++j) {
                float a = 0.f;
                #pragma unroll
                for (int o = 0; o < 16; ++o) a = fmaf(fc_w[j * 16 + o], q16[o], a);
                lg[j] = a;
            }
            const float m  = fmaxf(fmaxf(lg[0], lg[1]), fmaxf(lg[2], lg[3]));
            const float e0 = expf(lg[0] - m), e1 = expf(lg[1] - m);
            const float e2 = expf(lg[2] - m), e3 = expf(lg[3] - m);
            const float s  = e0 + e1 + e2 + e3;
            out[b * 4 + 0] = lg[0]; out[b * 4 + 1] = lg[1];
            out[b * 4 + 2] = lg[2]; out[b * 4 + 3] = lg[3];
            out[512 + b * 4 + 0] = e0 / s; out[512 + b * 4 + 1] = e1 / s;
            out[512 + b * 4 + 2] = e2 / s; out[512 + b * 4 + 3] = e3 / s;
        }
    }
}

extern "C" void kernel_launch(void* const* d_in, const int* in_sizes, int n_in,
                              void* d_out, int out_size, void* d_ws, size_t ws_size,
                              hipStream_t stream) {
    const float* layout  = (const float*)d_in[0];
    const float* heatmap = (const float*)d_in[1];
    const float* h_w     = (const float*)d_in[2];
    const float* h_b     = (const float*)d_in[3];
    const float* r_w     = (const float*)d_in[4];
    const float* q_w     = (const float*)d_in[5];
    const float* w       = (const float*)d_in[6];
    const float* fc_w    = (const float*)d_in[7];
    const int*   S1      = (const int*)d_in[8];
    const int*   S2      = (const int*)d_in[9];
    float* out = (float*)d_out;

    hipLaunchKernelGGL(vin_kernel, dim3(BB), dim3(NT), 0, stream,
                       layout, heatmap, h_w, h_b, r_w, q_w, w, fc_w, S1, S2, out);
}

// Round 3
// 140.514 us; speedup vs baseline: 1.1703x; 1.1647x over previous
//
#include <hip/hip_runtime.h>
#include <math.h>

#define BB 128
#define HH 64
#define WW 64
#define LH 150
#define KK 30
#define PW 66          // padded LDS row stride (64 + 2 border)
#define NT 1024
#define CROWS 50       // chunk-kernel staged rows (48 v-rows + 2 ring)

// ---- one conv channel over 3 pixels: a = BASE + conv3x3(vn, WSRC[o]) ----
#define CH_STEP3(o, WSRC, BASEo, POSTM)                                 \
  do {                                                                  \
    const float* wp_ = (WSRC) + (o) * 9;                                \
    const float w0_ = wp_[0], w1_ = wp_[1], w2_ = wp_[2];               \
    const float w3_ = wp_[3], w4_ = wp_[4], w5_ = wp_[5];               \
    const float w6_ = wp_[6], w7_ = wp_[7], w8_ = wp_[8];               \
    _Pragma("unroll")                                                   \
    for (int p_ = 0; p_ < 3; ++p_) {                                    \
      float a_ = BASEo;                                                 \
      a_ = fmaf(w0_, vn[p_ + 0][0], a_);                                \
      a_ = fmaf(w1_, vn[p_ + 0][1], a_);                                \
      a_ = fmaf(w2_, vn[p_ + 0][2], a_);                                \
      a_ = fmaf(w3_, vn[p_ + 1][0], a_);                                \
      a_ = fmaf(w4_, vn[p_ + 1][1], a_);                                \
      a_ = fmaf(w5_, vn[p_ + 1][2], a_);                                \
      a_ = fmaf(w6_, vn[p_ + 2][0], a_);                                \
      a_ = fmaf(w7_, vn[p_ + 2][1], a_);                                \
      a_ = fmaf(w8_, vn[p_ + 2][2], a_);                                \
      POSTM(o, p_, a_);                                                 \
    }                                                                   \
  } while (0)

#define POST_RQ(o, p, a) do { rq[o][p] = (a); vmax[p] = ((o) == 0) ? (a) : fmaxf(vmax[p], (a)); } while (0)
#define POST_VI(o, p, a) do { vm2[p] = ((o) == 0) ? (a) : fmaxf(vm2[p], (a)); } while (0)

// ================= prologue: r = collapsed conv(X); write r, out_r, out_h ==
__global__ __launch_bounds__(NT, 4)
void vin_prologue(const float* __restrict__ layout,
                  const float* __restrict__ heatmap,
                  const float* __restrict__ h_w,
                  const float* __restrict__ h_b,
                  const float* __restrict__ r_w,
                  float* __restrict__ rg,
                  float* __restrict__ out)
{
    const int b   = blockIdx.x;
    const int tid = threadIdx.x;
    const int tx  = tid & 63;
    const int ty  = tid >> 6;
    const int y0  = ty * 4;

    __shared__ float rh_s[28];
    __shared__ float sA[PW * PW];
    __shared__ float sB[PW * PW];
    __shared__ float sC[PW * PW];

    // collapse 150-ch h-conv + 1x1 r-conv into one 3->1 channel 3x3 conv
    if (tid < 28) {
        float s = 0.f;
        if (tid < 27) {
            for (int c = 0; c < LH; ++c) s += r_w[c] * h_w[c * 27 + tid];
        } else {
            for (int c = 0; c < LH; ++c) s += r_w[c] * h_b[c];
        }
        rh_s[tid] = s;
    }
    for (int i = tid; i < PW * PW; i += NT) { sA[i] = 0.f; sB[i] = 0.f; sC[i] = 0.f; }
    __syncthreads();

    const float* X0 = layout  + (size_t)b * 2 * HH * WW;
    const float* X1 = X0 + HH * WW;
    const float* X2 = heatmap + (size_t)b * HH * WW;
    for (int i = tid; i < HH * WW; i += NT) {
        const int y = i >> 6, x = i & 63;
        const int d = (y + 1) * PW + (x + 1);
        sA[d] = X0[i]; sB[d] = X1[i]; sC[d] = X2[i];
    }
    __syncthreads();

    float r4[4];
    {
        const float rb_ = rh_s[27];
        #pragma unroll
        for (int p = 0; p < 4; ++p) r4[p] = rb_;
        #pragma unroll
        for (int c = 0; c < 3; ++c) {
            const float* S = (c == 0) ? sA : ((c == 1) ? sB : sC);
            float xn[6][3];
            #pragma unroll
            for (int i = 0; i < 6; ++i)
                #pragma unroll
                for (int j = 0; j < 3; ++j)
                    xn[i][j] = S[(y0 + i) * PW + (tx + j)];
            #pragma unroll
            for (int p = 0; p < 4; ++p)
                #pragma unroll
                for (int dy = 0; dy < 3; ++dy)
                    #pragma unroll
                    for (int dx = 0; dx < 3; ++dx)
                        r4[p] = fmaf(rh_s[c * 9 + dy * 3 + dx], xn[p + dy][dx], r4[p]);
        }
    }

    float* out_r = out + 1024 + (size_t)BB * HH * WW + (size_t)b * HH * WW;
    float* out_h = out + 1024 + (size_t)2 * BB * HH * WW + (size_t)b * HH * WW;
    #pragma unroll
    for (int p = 0; p < 4; ++p) {
        const int y = y0 + p;
        rg[b * 4096 + y * 64 + tx] = r4[p];
        out_r[y * 64 + tx]         = r4[p];
    }
    for (int i = tid; i < HH * WW; i += NT) out_h[i] = X2[i];
}

// ========== chunk: stage r(+v), compute rq (and v0 if FIRST), NIT sweeps ====
template<int NIT, bool FIRST, bool LAST>
__global__ __launch_bounds__(NT, 4)
void vin_chunk(const float* __restrict__ rg,
               float* __restrict__ vg,
               const float* __restrict__ q_w,
               const float* __restrict__ w,
               const float* __restrict__ fc_w,
               const int* __restrict__ S1,
               const int* __restrict__ S2,
               float* __restrict__ out)
{
    const int b2   = blockIdx.x;
    const int b    = b2 >> 1;
    const int half = b2 & 1;
    const int vlo  = half ? 16 : 0;          // image row of LDS row 1
    const int tid  = threadIdx.x;
    const int tx   = tid & 63;
    const int ty   = tid >> 6;               // 0..15
    const int r0   = 3 * ty;                 // my v rows are LDS rows 1+r0 .. 3+r0

    __shared__ float r_s[CROWS * PW];
    __shared__ float va[CROWS * PW];
    __shared__ float vb[CROWS * PW];

    for (int i = tid; i < CROWS * PW; i += NT) { r_s[i] = 0.f; va[i] = 0.f; vb[i] = 0.f; }
    __syncthreads();

    // stage r rows (image vlo-1 .. vlo+48), zero outside image
    for (int i = tid; i < CROWS * 64; i += NT) {
        const int row = i >> 6, col = i & 63;
        const int ir = vlo - 1 + row;
        if (ir >= 0 && ir < HH)
            r_s[row * PW + col + 1] = rg[b * 4096 + ir * 64 + col];
    }
    if (!FIRST) {
        // stage v rows (image vlo .. vlo+47) into LDS rows 1..48
        for (int i = tid; i < 48 * 64; i += NT) {
            const int row = i >> 6, col = i & 63;
            va[(row + 1) * PW + col + 1] = vg[b * 4096 + (vlo + row) * 64 + col];
        }
    }
    __syncthreads();

    // rq[o][p] = conv3x3(r, q_w[o]) at my 3 pixels; v0 = max_o rq (FIRST only)
    float rq[16][3];
    {
        float vn[5][3];
        #pragma unroll
        for (int i = 0; i < 5; ++i)
            #pragma unroll
            for (int j = 0; j < 3; ++j)
                vn[i][j] = r_s[(r0 + i) * PW + tx + j];
        float vmax[3];
        CH_STEP3(0,  q_w, 0.f, POST_RQ);  CH_STEP3(1,  q_w, 0.f, POST_RQ);
        CH_STEP3(2,  q_w, 0.f, POST_RQ);  CH_STEP3(3,  q_w, 0.f, POST_RQ);
        CH_STEP3(4,  q_w, 0.f, POST_RQ);  CH_STEP3(5,  q_w, 0.f, POST_RQ);
        CH_STEP3(6,  q_w, 0.f, POST_RQ);  CH_STEP3(7,  q_w, 0.f, POST_RQ);
        CH_STEP3(8,  q_w, 0.f, POST_RQ);  CH_STEP3(9,  q_w, 0.f, POST_RQ);
        CH_STEP3(10, q_w, 0.f, POST_RQ);  CH_STEP3(11, q_w, 0.f, POST_RQ);
        CH_STEP3(12, q_w, 0.f, POST_RQ);  CH_STEP3(13, q_w, 0.f, POST_RQ);
        CH_STEP3(14, q_w, 0.f, POST_RQ);  CH_STEP3(15, q_w, 0.f, POST_RQ);
        if (FIRST) {
            #pragma unroll
            for (int p = 0; p < 3; ++p)
                va[(1 + r0 + p) * PW + tx + 1] = vmax[p];
        }
    }
    __syncthreads();

    // NIT value-iteration sweeps
    float* vcur = va;
    float* vnxt = vb;
    #pragma unroll 1
    for (int it = 0; it < NIT; ++it) {
        float vn[5][3];
        #pragma unroll
        for (int i = 0; i < 5; ++i)
            #pragma unroll
            for (int j = 0; j < 3; ++j)
                vn[i][j] = vcur[(r0 + i) * PW + tx + j];
        float vm2[3];
        CH_STEP3(0,  w, rq[0][p_],  POST_VI);  CH_STEP3(1,  w, rq[1][p_],  POST_VI);
        CH_STEP3(2,  w, rq[2][p_],  POST_VI);  CH_STEP3(3,  w, rq[3][p_],  POST_VI);
        CH_STEP3(4,  w, rq[4][p_],  POST_VI);  CH_STEP3(5,  w, rq[5][p_],  POST_VI);
        CH_STEP3(6,  w, rq[6][p_],  POST_VI);  CH_STEP3(7,  w, rq[7][p_],  POST_VI);
        CH_STEP3(8,  w, rq[8][p_],  POST_VI);  CH_STEP3(9,  w, rq[9][p_],  POST_VI);
        CH_STEP3(10, w, rq[10][p_], POST_VI);  CH_STEP3(11, w, rq[11][p_], POST_VI);
        CH_STEP3(12, w, rq[12][p_], POST_VI);  CH_STEP3(13, w, rq[13][p_], POST_VI);
        CH_STEP3(14, w, rq[14][p_], POST_VI);  CH_STEP3(15, w, rq[15][p_], POST_VI);
        #pragma unroll
        for (int p = 0; p < 3; ++p)
            vnxt[(1 + r0 + p) * PW + tx + 1] = vm2[p];
        __syncthreads();
        float* t = vcur; vcur = vnxt; vnxt = t;
    }

    // write back core rows (always valid: halo 16 >= NIT+1)
    if (!LAST) {
        for (int i = tid; i < 32 * 64; i += NT) {
            const int ir = half * 32 + (i >> 6);
            const int col = i & 63;
            vg[b * 4096 + ir * 64 + col] = vcur[(ir - vlo + 1) * PW + col + 1];
        }
    } else {
        float* out_v = out + 1024 + (size_t)b * HH * WW;
        for (int i = tid; i < 32 * 64; i += NT) {
            const int ir = half * 32 + (i >> 6);
            const int col = i & 63;
            out_v[ir * 64 + col] = vcur[(ir - vlo + 1) * PW + col + 1];
        }
        const int s1 = S1[b];
        if (tid == 0 && s1 >= half * 32 && s1 < half * 32 + 32) {
            const int s2 = S2[b];
            float q16[16];
            #pragma unroll
            for (int o = 0; o < 16; ++o) {
                float acc = 0.f;
                #pragma unroll
                for (int dy = 0; dy < 3; ++dy)
                    #pragma unroll
                    for (int dx = 0; dx < 3; ++dx) {
                        const int li = (s1 + dy - vlo) * PW + (s2 + dx);
                        acc = fmaf(q_w[o * 9 + dy * 3 + dx], r_s[li], acc);
                        acc = fmaf(w[o * 9 + dy * 3 + dx],  vcur[li], acc);
                    }
                q16[o] = acc;
            }
            float lg[4];
            #pragma unroll
            for (int j = 0; j < 4; ++j) {
                float a = 0.f;
                #pragma unroll
                for (int o = 0; o < 16; ++o) a = fmaf(fc_w[j * 16 + o], q16[o], a);
                lg[j] = a;
            }
            const float m  = fmaxf(fmaxf(lg[0], lg[1]), fmaxf(lg[2], lg[3]));
            const float e0 = expf(lg[0] - m), e1 = expf(lg[1] - m);
            const float e2 = expf(lg[2] - m), e3 = expf(lg[3] - m);
            const float s  = e0 + e1 + e2 + e3;
            out[b * 4 + 0] = lg[0]; out[b * 4 + 1] = lg[1];
            out[b * 4 + 2] = lg[2]; out[b * 4 + 3] = lg[3];
            out[512 + b * 4 + 0] = e0 / s; out[512 + b * 4 + 1] = e1 / s;
            out[512 + b * 4 + 2] = e2 / s; out[512 + b * 4 + 3] = e3 / s;
        }
    }
}

extern "C" void kernel_launch(void* const* d_in, const int* in_sizes, int n_in,
                              void* d_out, int out_size, void* d_ws, size_t ws_size,
                              hipStream_t stream) {
    const float* layout  = (const float*)d_in[0];
    const float* heatmap = (const float*)d_in[1];
    const float* h_w     = (const float*)d_in[2];
    const float* h_b     = (const float*)d_in[3];
    const float* r_w     = (const float*)d_in[4];
    const float* q_w     = (const float*)d_in[5];
    const float* w       = (const float*)d_in[6];
    const float* fc_w    = (const float*)d_in[7];
    const int*   S1      = (const int*)d_in[8];
    const int*   S2      = (const int*)d_in[9];
    float* out = (float*)d_out;

    float* rg = (float*)d_ws;                 // 128*4096 f32 = 2 MB
    float* vg = rg + (size_t)BB * HH * WW;    // 128*4096 f32 = 2 MB

    hipLaunchKernelGGL(vin_prologue, dim3(BB), dim3(NT), 0, stream,
                       layout, heatmap, h_w, h_b, r_w, rg, out);
    // 1 (v0 inside chunk0) + 15 + 14 = 30 = KK q/v steps
    hipLaunchKernelGGL((vin_chunk<15, true,  false>), dim3(2 * BB), dim3(NT), 0, stream,
                       rg, vg, q_w, w, fc_w, S1, S2, out);
    hipLaunchKernelGGL((vin_chunk<14, false, true>),  dim3(2 * BB), dim3(NT), 0, stream,
                       rg, vg, q_w, w, fc_w, S1, S2, out);
}

// Round 5
// 116.673 us; speedup vs baseline: 1.4094x; 1.2043x over previous
//
#include <hip/hip_runtime.h>
#include <math.h>

#define NT 1024
#define PW 66      // padded LDS row stride
#define RR 52      // LDS buffer rows (52 X rows / 50 r rows / 48 v rows + ring)

// Two launches: chunk<15,FIRST> then chunk<14,LAST>. 256 blocks, block = half image
// (32 core rows + 16-row internal halo). Wave = 16 pixel-cols x 4 channel-groups:
// lane (g,p): channels 4g..4g+3, col c=(wid&3)*16+p, rows band*12..band*12+11 (band=wid>>2).
// VI weights live in 36 VGPRs across all sweeps; rq[48] statically indexed.

template<int NIT, bool FIRST, bool LAST>
__global__ __launch_bounds__(NT, 4)
void vin_chunk(const float* __restrict__ layout,
               const float* __restrict__ heatmap,
               const float* __restrict__ h_w,
               const float* __restrict__ h_b,
               const float* __restrict__ r_w,
               const float* __restrict__ q_w,
               const float* __restrict__ w,
               const float* __restrict__ fc_w,
               const int* __restrict__ S1,
               const int* __restrict__ S2,
               float* __restrict__ vg,
               float* __restrict__ out)
{
    __shared__ float rh[28];
    __shared__ float r_s[RR * PW];   // X0, then r   (r_s row M <-> image row vlo-1+M)
    __shared__ float va[RR * PW];    // X1, then v ping (v row L <-> image row vlo+L-1)
    __shared__ float vb[RR * PW];    // X2, then v pong

    const int b2   = blockIdx.x;
    const int b    = b2 >> 1;
    const int half = b2 & 1;
    const int vlo  = half ? 16 : 0;
    const int tid  = threadIdx.x;

    // B0: zero everything (borders must be 0)
    for (int i = tid; i < RR * PW; i += NT) { r_s[i] = 0.f; va[i] = 0.f; vb[i] = 0.f; }
    __syncthreads();

    // collapse 150-ch h-conv + 1x1 r-conv into 28 coeffs (32 threads per coeff)
    if (tid < 896) {
        const int coeff = tid >> 5, j = tid & 31;
        float s = 0.f;
        for (int c = j; c < 150; c += 32)
            s += r_w[c] * ((coeff < 27) ? h_w[c * 27 + coeff] : h_b[c]);
        s += __shfl_xor(s, 1, 32);  s += __shfl_xor(s, 2, 32);
        s += __shfl_xor(s, 4, 32);  s += __shfl_xor(s, 8, 32);
        s += __shfl_xor(s, 16, 32);
        if (j == 0) rh[coeff] = s;
    }
    // stage X rows M=0..51 <-> image rows vlo-2..vlo+49 (zero OOB kept from memset)
    const float* X0 = layout  + (size_t)b * 2 * 4096;
    const float* X1 = X0 + 4096;
    const float* X2 = heatmap + (size_t)b * 4096;
    for (int i = tid; i < RR * 64; i += NT) {
        const int M = i >> 6, col = i & 63;
        const int ir = vlo - 2 + M;
        if (ir >= 0 && ir < 64) {
            const int s = ir * 64 + col, d = M * PW + col + 1;
            r_s[d] = X0[s]; va[d] = X1[s]; vb[d] = X2[s];
        }
    }
    __syncthreads();  // B1: X + rh ready

    // r (rows 0..49, cols 0..63) into registers; window top X-row == dest r-row
    float rv[4];
    int   rpx[4];
    #pragma unroll
    for (int k2 = 0; k2 < 4; ++k2) {
        const int i = tid + k2 * NT;
        rpx[k2] = -1;
        if (i < 50 * 64) {
            const int row = i >> 6, col = i & 63;
            float acc = rh[27];
            #pragma unroll
            for (int dy = 0; dy < 3; ++dy)
                #pragma unroll
                for (int dx = 0; dx < 3; ++dx) {
                    const int idx = (row + dy) * PW + col + dx;
                    acc = fmaf(rh[0 * 9 + dy * 3 + dx], r_s[idx], acc);
                    acc = fmaf(rh[1 * 9 + dy * 3 + dx], va[idx],  acc);
                    acc = fmaf(rh[2 * 9 + dy * 3 + dx], vb[idx],  acc);
                }
            const int ir = vlo - 1 + row;
            rv[k2]  = (ir >= 0 && ir < 64) ? acc : 0.f;  // true zero padding
            rpx[k2] = row * PW + col + 1;
        }
    }
    __syncthreads();  // B2: X consumed

    // overwrite: r -> r_s, re-zero v buffers
    for (int i = tid; i < RR * PW; i += NT) { va[i] = 0.f; vb[i] = 0.f; }
    #pragma unroll
    for (int k2 = 0; k2 < 4; ++k2) if (rpx[k2] >= 0) r_s[rpx[k2]] = rv[k2];
    __syncthreads();  // B3: r ready, v buffers zero

    // per-lane geometry
    const int wid  = tid >> 6, lane = tid & 63;
    const int g    = lane >> 4, p = lane & 15;
    const int c    = (wid & 3) * 16 + p;
    const int band = wid >> 2;
    const int rb0  = band * 12;      // conv-window top LDS row for j=0

    // stage v (non-FIRST) rows 1..48 <- vg image rows vlo..vlo+47
    if (!FIRST) {
        for (int i = tid; i < 48 * 64; i += NT) {
            const int L = (i >> 6) + 1, col = i & 63;
            va[L * PW + col + 1] = vg[b * 4096 + (vlo + L - 1) * 64 + col];
        }
    }

    // rq[cc*12+j] = conv3x3(r, q_w[4g+cc]) at (row 1+rb0+j, col c); v0 if FIRST
    float wq[36];
    #pragma unroll
    for (int t = 0; t < 36; ++t) wq[t] = q_w[g * 36 + t];

    float rq[48];
    {
        const float* rw = r_s + rb0 * PW + c;
        float a0[3], a1[3], a2[3];
        #pragma unroll
        for (int d = 0; d < 3; ++d) { a0[d] = rw[d]; a1[d] = rw[PW + d]; }
        #pragma unroll
        for (int j = 0; j < 12; ++j) {
            #pragma unroll
            for (int d = 0; d < 3; ++d) a2[d] = rw[(j + 2) * PW + d];
            #pragma unroll
            for (int cc = 0; cc < 4; ++cc) {
                float a = 0.f;
                #pragma unroll
                for (int d = 0; d < 3; ++d) {
                    a = fmaf(wq[cc * 9 + d],     a0[d], a);
                    a = fmaf(wq[cc * 9 + 3 + d], a1[d], a);
                    a = fmaf(wq[cc * 9 + 6 + d], a2[d], a);
                }
                rq[cc * 12 + j] = a;
            }
            if (FIRST) {
                float m = fmaxf(fmaxf(rq[0 * 12 + j], rq[1 * 12 + j]),
                                fmaxf(rq[2 * 12 + j], rq[3 * 12 + j]));
                m = fmaxf(m, __shfl_xor(m, 16));
                m = fmaxf(m, __shfl_xor(m, 32));
                if (g == 0) va[(1 + rb0 + j) * PW + c + 1] = m;
            }
            #pragma unroll
            for (int d = 0; d < 3; ++d) { a0[d] = a1[d]; a1[d] = a2[d]; }
        }
    }

    float wv[36];
    #pragma unroll
    for (int t = 0; t < 36; ++t) wv[t] = w[g * 36 + t];
    __syncthreads();  // B4: v0 / staged v ready

    // NIT sweeps
    float* vcur = va;
    float* vnxt = vb;
    #pragma unroll 1
    for (int it = 0; it < NIT; ++it) {
        const float* vw = vcur + rb0 * PW + c;
        float a0[3], a1[3], a2[3];
        #pragma unroll
        for (int d = 0; d < 3; ++d) { a0[d] = vw[d]; a1[d] = vw[PW + d]; }
        #pragma unroll
        for (int j = 0; j < 12; ++j) {
            #pragma unroll
            for (int d = 0; d < 3; ++d) a2[d] = vw[(j + 2) * PW + d];
            float q0 = rq[0 * 12 + j], q1 = rq[1 * 12 + j];
            float q2 = rq[2 * 12 + j], q3 = rq[3 * 12 + j];
            #pragma unroll
            for (int d = 0; d < 3; ++d) {
                q0 = fmaf(wv[0 + d],  a0[d], q0); q0 = fmaf(wv[3 + d],  a1[d], q0); q0 = fmaf(wv[6 + d],  a2[d], q0);
                q1 = fmaf(wv[9 + d],  a0[d], q1); q1 = fmaf(wv[12 + d], a1[d], q1); q1 = fmaf(wv[15 + d], a2[d], q1);
                q2 = fmaf(wv[18 + d], a0[d], q2); q2 = fmaf(wv[21 + d], a1[d], q2); q2 = fmaf(wv[24 + d], a2[d], q2);
                q3 = fmaf(wv[27 + d], a0[d], q3); q3 = fmaf(wv[30 + d], a1[d], q3); q3 = fmaf(wv[33 + d], a2[d], q3);
            }
            float m = fmaxf(fmaxf(q0, q1), fmaxf(q2, q3));
            m = fmaxf(m, __shfl_xor(m, 16));
            m = fmaxf(m, __shfl_xor(m, 32));
            if (g == 0) vnxt[(1 + rb0 + j) * PW + c + 1] = m;
            #pragma unroll
            for (int d = 0; d < 3; ++d) { a0[d] = a1[d]; a1[d] = a2[d]; }
        }
        __syncthreads();
        float* t = vcur; vcur = vnxt; vnxt = t;
    }

    // writeback core rows (image half*32 .. half*32+31; L = ir - vlo + 1)
    if (!LAST) {
        for (int i = tid; i < 32 * 64; i += NT) {
            const int ir = half * 32 + (i >> 6), col = i & 63;
            vg[b * 4096 + ir * 64 + col] = vcur[(ir - vlo + 1) * PW + col + 1];
        }
    } else {
        float* out_v = out + 1024 + (size_t)b * 4096;
        for (int i = tid; i < 32 * 64; i += NT) {
            const int ir = half * 32 + (i >> 6), col = i & 63;
            out_v[ir * 64 + col] = vcur[(ir - vlo + 1) * PW + col + 1];
        }
    }
    if (FIRST) {
        float* out_r = out + 1024 + (size_t)128 * 4096 + (size_t)b * 4096;
        float* out_h = out + 1024 + (size_t)256 * 4096 + (size_t)b * 4096;
        for (int i = tid; i < 32 * 64; i += NT) {
            const int ir = half * 32 + (i >> 6), col = i & 63;
            out_r[ir * 64 + col] = r_s[(ir - vlo + 1) * PW + col + 1];
            out_h[ir * 64 + col] = X2[ir * 64 + col];
        }
    }

    if (LAST) {
        const int s1 = S1[b], s2 = S2[b];
        if ((s1 >> 5) == half && tid == 0) {
            float q16[16];
            #pragma unroll
            for (int o = 0; o < 16; ++o) {
                float acc = 0.f;
                #pragma unroll
                for (int dy = 0; dy < 3; ++dy)
                    #pragma unroll
                    for (int dx = 0; dx < 3; ++dx) {
                        const int li = (s1 + dy - vlo) * PW + s2 + dx;   // row s1+dy-1 -> L = s1+dy-1-vlo+1
                        acc = fmaf(q_w[o * 9 + dy * 3 + dx], r_s[li], acc);
                        acc = fmaf(w[o * 9 + dy * 3 + dx],  vcur[li], acc);
                    }
                q16[o] = acc;
            }
            float lg[4];
            #pragma unroll
            for (int j = 0; j < 4; ++j) {
                float a = 0.f;
                #pragma unroll
                for (int o = 0; o < 16; ++o) a = fmaf(fc_w[j * 16 + o], q16[o], a);
                lg[j] = a;
            }
            const float m  = fmaxf(fmaxf(lg[0], lg[1]), fmaxf(lg[2], lg[3]));
            const float e0 = expf(lg[0] - m), e1 = expf(lg[1] - m);
            const float e2 = expf(lg[2] - m), e3 = expf(lg[3] - m);
            const float s  = e0 + e1 + e2 + e3;
            out[b * 4 + 0] = lg[0]; out[b * 4 + 1] = lg[1];
            out[b * 4 + 2] = lg[2]; out[b * 4 + 3] = lg[3];
            out[512 + b * 4 + 0] = e0 / s; out[512 + b * 4 + 1] = e1 / s;
            out[512 + b * 4 + 2] = e2 / s; out[512 + b * 4 + 3] = e3 / s;
        }
    }
}

extern "C" void kernel_launch(void* const* d_in, const int* in_sizes, int n_in,
                              void* d_out, int out_size, void* d_ws, size_t ws_size,
                              hipStream_t stream) {
    const float* layout  = (const float*)d_in[0];
    const float* heatmap = (const float*)d_in[1];
    const float* h_w     = (const float*)d_in[2];
    const float* h_b     = (const float*)d_in[3];
    const float* r_w     = (const float*)d_in[4];
    const float* q_w     = (const float*)d_in[5];
    const float* w       = (const float*)d_in[6];
    const float* fc_w    = (const float*)d_in[7];
    const int*   S1      = (const int*)d_in[8];
    const int*   S2      = (const int*)d_in[9];
    float* out = (float*)d_out;
    float* vg  = (float*)d_ws;   // 128*4096 f32 = 2 MB

    hipLaunchKernelGGL((vin_chunk<15, true,  false>), dim3(256), dim3(NT), 0, stream,
                       layout, heatmap, h_w, h_b, r_w, q_w, w, fc_w, S1, S2, vg, out);
    hipLaunchKernelGGL((vin_chunk<14, false, true>),  dim3(256), dim3(NT), 0, stream,
                       layout, heatmap, h_w, h_b, r_w, q_w, w, fc_w, S1, S2, vg, out);
}